// Round 9
// baseline (81.425 us; speedup 1.0000x reference)
//
#include <hip/hip_runtime.h>
#include <math.h>

// Problem constants (match reference)
#define Lp 1024
#define Bp 64
#define IT 64             // i-rows per block
#define NIT 16            // Lp / IT
#define DMAX 512          // offsets d = 1..512
#define SLOTS (IT + DMAX) // 576 staged columns (ring)

// Offset-ring decomposition: block = (batch b, i-tile of 64 rows). Each pair
// (i, (i+d) mod 1024), d=1..512, covers every unordered pair exactly once,
// except d=512 which is covered twice -> its contribution gets weight 0.5
// (peeled into a separate accumulator; no inner-loop cost).
// Separable sum (validated R8, absmax 0.0):
//   sum_ord mi mj (dy-dx)^2 = sepx + sepy - 4 * sum_unord mi mj sqrt(d2x*d2y)
//   sep = 2*(nv*Sum m|p|^2 - |Sum m p|^2)   (exact, O(L) stats)
// Main loop per pair: 14 scalar VALU + 1 v_sqrt (pk-f32 falsified in R8:
// CDNA4 packed fp32 is NOT dual-rate; 157.3 TF spec = scalar rate).
// Grid = 64x16 = 1024 blocks = exactly 4/CU, 16 waves/CU: no occupancy
// overcommit, no straggler tail (R4-R8 ran 9 blocks/CU vs 8 resident).
// NOTE (R5/R6): no per-block __threadfence fusion - agent-scope release
// forces an L2 writeback per block on gfx950 (~+30 us). Two launches win.
__global__ __launch_bounds__(256) void drmsd_main(
    const float* __restrict__ x, const float* __restrict__ y,
    float* __restrict__ partials, float* __restrict__ statsbuf)
{
    __shared__ __align__(16) float4 X4[SLOTS];  // (x0,x1,x2, m)
    __shared__ __align__(16) float4 Y4[SLOTS];  // (y0,y1,y2, m)
    __shared__ float red[4];

    const int b    = blockIdx.x;   // batch
    const int tile = blockIdx.y;   // i-tile
    const int i0   = tile * IT;
    const int t    = threadIdx.x;

    // ---- stage 576 ring slots; slot s holds row (i0+s) mod 1024 ----
    float st[9];
#pragma unroll
    for (int k = 0; k < 3; ++k) {
        const int s = t + (k << 8);
        if (s < SLOTS) {
            const int row = (i0 + s) & (Lp - 1);
            const float* px = x + (size_t)row * (Bp * 3) + (size_t)b * 3;
            const float* py = y + (size_t)row * (Bp * 3) + (size_t)b * 3;
            const float x0 = px[0], x1 = px[1], x2 = px[2];
            const float y0 = py[0], y1 = py[1], y2 = py[2];
            const float m  = ((y0 + y1 + y2) != 0.0f) ? 1.0f : 0.0f;
            X4[s] = make_float4(x0, x1, x2, m);
            Y4[s] = make_float4(y0, y1, y2, m);
            if (k == 0 && t < IT) {   // this thread's slot == i-row t: stats
                st[0] = m;
                st[1] = m * (x0*x0 + x1*x1 + x2*x2);
                st[2] = m * x0; st[3] = m * x1; st[4] = m * x2;
                st[5] = m * (y0*y0 + y1*y1 + y2*y2);
                st[6] = m * y0; st[7] = m * y1; st[8] = m * y2;
            }
        }
    }
    // per-(b,tile) masked stats: wave 0 (threads 0..63), covers each row once
    if (t < IT) {
#pragma unroll
        for (int kk = 0; kk < 9; ++kk) {
            float v = st[kk];
#pragma unroll
            for (int off = 32; off > 0; off >>= 1) v += __shfl_down(v, off, 64);
            st[kk] = v;
        }
        if (t == 0) {
#pragma unroll
            for (int kk = 0; kk < 9; ++kk)
                statsbuf[((size_t)tile * 9 + kk) * Bp + b] = st[kk];  // [tile][k][b]
        }
    }
    __syncthreads();

    // ---- main loop: lane l = i-row, wave wv covers d in [1+128wv, 128+128wv]
    const int l  = t & 63;
    const int wv = t >> 6;
    const float4 xi = X4[l];
    const float4 yi = Y4[l];
    const float  mi = xi.w;
    const int sbase = l + 1 + (wv << 7);   // slot for dd=0

    float acc = 0.0f, accL = 0.0f;
#pragma unroll 4
    for (int dd = 0; dd < 127; ++dd) {
        const float4 xj = X4[sbase + dd];
        const float4 yj = Y4[sbase + dd];
        const float ax = xi.x - xj.x, ay = xi.y - xj.y, az = xi.z - xj.z;
        const float d2x = fmaf(ax, ax, fmaf(ay, ay, az * az));
        const float bx = yi.x - yj.x, by = yi.y - yj.y, bz = yi.z - yj.z;
        const float d2y = fmaf(bx, bx, fmaf(by, by, bz * bz));
        const float sq = __builtin_amdgcn_sqrtf(d2x * d2y);  // >= 0 exactly
        acc = fmaf(yj.w, sq, acc);                            // col mask
    }
    {   // peeled dd=127: for wave 3 this is d=512 (double-covered -> 0.5)
        const float4 xj = X4[sbase + 127];
        const float4 yj = Y4[sbase + 127];
        const float ax = xi.x - xj.x, ay = xi.y - xj.y, az = xi.z - xj.z;
        const float d2x = fmaf(ax, ax, fmaf(ay, ay, az * az));
        const float bx = yi.x - yj.x, by = yi.y - yj.y, bz = yi.z - yj.z;
        const float d2y = fmaf(bx, bx, fmaf(by, by, bz * bz));
        const float sq = __builtin_amdgcn_sqrtf(d2x * d2y);
        accL = yj.w * sq;
    }
    const float wlast = (wv == 3) ? 0.5f : 1.0f;
    float total = mi * fmaf(wlast, accL, acc);   // row mask

    // ---- block reduction ----
#pragma unroll
    for (int off = 32; off > 0; off >>= 1)
        total += __shfl_down(total, off, 64);
    if ((t & 63) == 0) red[wv] = total;
    __syncthreads();
    if (t == 0)
        partials[(size_t)tile * Bp + b] = red[0] + red[1] + red[2] + red[3];
}

__global__ __launch_bounds__(256) void drmsd_final(
    const float* __restrict__ partials, const float* __restrict__ statsbuf,
    float* __restrict__ out)
{
    __shared__ float s_cross[256];
    __shared__ float s_st[256][9];
    const int t    = threadIdx.x;
    const int lane = t & 63;       // batch
    const int q    = t >> 6;       // wave q handles tiles q*4 .. q*4+3
    float c = 0.0f;
    float a[9] = {0.f,0.f,0.f,0.f,0.f,0.f,0.f,0.f,0.f};
#pragma unroll
    for (int k = 0; k < 4; ++k) {
        const int tile = q * 4 + k;
        c += partials[(size_t)tile * Bp + lane];             // coalesced
#pragma unroll
        for (int kk = 0; kk < 9; ++kk)
            a[kk] += statsbuf[((size_t)tile * 9 + kk) * Bp + lane];  // coalesced
    }
    s_cross[t] = c;
#pragma unroll
    for (int kk = 0; kk < 9; ++kk) s_st[t][kk] = a[kk];
    __syncthreads();
    if (t < 64) {
        const float cross = s_cross[t] + s_cross[t + 64] + s_cross[t + 128] + s_cross[t + 192];
        float stt[9];
#pragma unroll
        for (int kk = 0; kk < 9; ++kk)
            stt[kk] = s_st[t][kk] + s_st[t + 64][kk] + s_st[t + 128][kk] + s_st[t + 192][kk];
        const float nv   = stt[0];
        const float sepx = 2.0f * (nv * stt[1] - (stt[2]*stt[2] + stt[3]*stt[3] + stt[4]*stt[4]));
        const float sepy = 2.0f * (nv * stt[5] - (stt[6]*stt[6] + stt[7]*stt[7] + stt[8]*stt[8]));
        const float Sb = fmaxf(sepx + sepy - 4.0f * cross, 0.0f);
        float pb = sqrtf(Sb);
#pragma unroll
        for (int off = 32; off > 0; off >>= 1)
            pb += __shfl_down(pb, off, 64);
        if (t == 0) {
            const double denom = sqrt((double)Lp * (double)Lp / 2.0 - (double)Lp);
            out[0] = (float)((double)pb / denom / (double)Bp);
        }
    }
}

extern "C" void kernel_launch(void* const* d_in, const int* in_sizes, int n_in,
                              void* d_out, int out_size, void* d_ws, size_t ws_size,
                              hipStream_t stream) {
    const float* x = (const float*)d_in[0];
    const float* y = (const float*)d_in[1];
    float* out      = (float*)d_out;
    float* partials = (float*)d_ws;                       // 16*64 floats = 4096 B
    float* statsbuf = (float*)((char*)d_ws + 4096);       // 16*9*64 floats = 36864 B

    dim3 grid(Bp, NIT);
    drmsd_main<<<grid, 256, 0, stream>>>(x, y, partials, statsbuf);
    drmsd_final<<<1, 256, 0, stream>>>(partials, statsbuf, out);
}